// Round 2
// baseline (385.385 us; speedup 1.0000x reference)
//
#include <hip/hip_runtime.h>
#include <hip/hip_bf16.h>

typedef unsigned int u32;
typedef unsigned short u16;
typedef __attribute__((ext_vector_type(8))) short short8;   // 8 bf16 (4 VGPRs), MFMA A/B frag
typedef __attribute__((ext_vector_type(4))) float f32x4;    // MFMA C/D frag

#define NEG_SCORE (-100000.0f)

// ---------- bf16 helpers (raw u16 representation) ----------
__device__ __forceinline__ float bflo(u32 u) { return __uint_as_float(u << 16); }
__device__ __forceinline__ float bfhi(u32 u) { return __uint_as_float(u & 0xffff0000u); }
__device__ __forceinline__ u16 f2bf(float f) {
    u32 u = __float_as_uint(f);
    u32 r = (u + 0x7fffu + ((u >> 16) & 1u)) >> 16;   // round-to-nearest-even
    return (u16)r;
}

// ---------- async global->LDS 16B copy ----------
__device__ __forceinline__ void async16(const u16* g, u16* l) {
    __builtin_amdgcn_global_load_lds(
        (const __attribute__((address_space(1))) u32*)g,
        (__attribute__((address_space(3))) u32*)l,
        16, 0, 0);
}

// =====================================================================
// fp32 -> bf16 bulk convert. Each thread converts 8 elements (n % 8 == 0).
// =====================================================================
__global__ __launch_bounds__(256) void f32_to_bf16_kernel(
    const float* __restrict__ src, u16* __restrict__ dst)
{
    const int i = blockIdx.x * 256 + threadIdx.x;
    const float4* s4 = (const float4*)src;
    float4 a = s4[2 * i + 0];
    float4 b = s4[2 * i + 1];
    uint4 o;
    o.x = (u32)f2bf(a.x) | ((u32)f2bf(a.y) << 16);
    o.y = (u32)f2bf(a.z) | ((u32)f2bf(a.w) << 16);
    o.z = (u32)f2bf(b.x) | ((u32)f2bf(b.y) << 16);
    o.w = (u32)f2bf(b.z) | ((u32)f2bf(b.w) << 16);
    ((uint4*)dst)[i] = o;
}

// =====================================================================
// GEMM: C(M,N) = A(M,K) * Bt(N,K)^T + bias(N); bf16 A/B, fp32 bias/accum.
// OUT_BF16 selects bf16 or fp32 C. Requires M%128==0, N%128==0, K%32==0.
// m97-style: 128x128 tile, BK=32, 256 threads = 4 waves, each wave 64x64.
// =====================================================================
template <bool OUT_BF16>
__global__ __launch_bounds__(256) void gemm_bt_bias(
    const u16* __restrict__ A, const u16* __restrict__ Bt,
    const float* __restrict__ bias, void* __restrict__ Cv,
    int M, int N, int K)
{
    __shared__ u16 sA[128 * 32];   // 8 KB, row-major 128 rows x 32 cols
    __shared__ u16 sB[128 * 32];

    const int t    = threadIdx.x;
    const int m0   = blockIdx.y * 128;
    const int n0   = blockIdx.x * 128;
    const int lane = t & 63;
    const int wv   = t >> 6;
    const int wm   = (wv & 1) * 64;
    const int wn   = (wv >> 1) * 64;
    const int lr   = lane & 15;
    const int quad = lane >> 4;

    // staging: thread t covers bytes [t*16, t*16+16) of each 8KB half-tile
    const u16* pa = A  + (size_t)(m0 + (t >> 2)) * K + ((t & 3) << 3);
    const u16* pb = Bt + (size_t)(n0 + (t >> 2)) * K + ((t & 3) << 3);
    u16* la = &sA[t * 8];
    u16* lb = &sB[t * 8];
    const size_t half = (size_t)64 * K;

    const f32x4 zero4 = {0.f, 0.f, 0.f, 0.f};
    f32x4 acc[4][4];
#pragma unroll
    for (int mt = 0; mt < 4; mt++)
#pragma unroll
        for (int nt = 0; nt < 4; nt++) acc[mt][nt] = zero4;

    for (int kk = 0; kk < K; kk += 32) {
        async16(pa + kk, la);
        async16(pa + kk + half, la + 2048);
        async16(pb + kk, lb);
        async16(pb + kk + half, lb + 2048);
        __syncthreads();   // compiler drains vmcnt before s_barrier

        short8 af[4], bfr[4];
#pragma unroll
        for (int mt = 0; mt < 4; mt++)
            af[mt] = *(const short8*)&sA[(wm + mt * 16 + lr) * 32 + quad * 8];
#pragma unroll
        for (int nt = 0; nt < 4; nt++)
            bfr[nt] = *(const short8*)&sB[(wn + nt * 16 + lr) * 32 + quad * 8];

#pragma unroll
        for (int mt = 0; mt < 4; mt++)
#pragma unroll
            for (int nt = 0; nt < 4; nt++)
                acc[mt][nt] = __builtin_amdgcn_mfma_f32_16x16x32_bf16(
                    af[mt], bfr[nt], acc[mt][nt], 0, 0, 0);
        __syncthreads();
    }

    float bv[4];
#pragma unroll
    for (int nt = 0; nt < 4; nt++)
        bv[nt] = bias[n0 + wn + nt * 16 + lr];

    // D layout: lane holds D[m = quad*4+i][n = lane&15] for i=0..3
#pragma unroll
    for (int mt = 0; mt < 4; mt++) {
#pragma unroll
        for (int i = 0; i < 4; i++) {
            size_t row = (size_t)(m0 + wm + mt * 16 + quad * 4 + i);
#pragma unroll
            for (int nt = 0; nt < 4; nt++) {
                float v = acc[mt][nt][i] + bv[nt];
                size_t idx = row * N + n0 + wn + nt * 16 + lr;
                if (OUT_BF16) ((u16*)Cv)[idx] = f2bf(v);
                else          ((float*)Cv)[idx] = v;
            }
        }
    }
}

// =====================================================================
// Sliding-window attention. qkv rows: (b*L + l) * 3072, head h occupies
// cols [h*192, h*192+192) split q|k|v at 64/64/64. One thread per query,
// 64-thread blocks, two-pass online softmax, fp32 accumulation.
// values layout: (b*L + l) * 1024 + h*64 + d  (A-matrix for output GEMM)
// =====================================================================
#define ATT_L 2048
#define ATT_C3 3072

__device__ __forceinline__ float dot64(const float* qf, const u16* krow) {
    const uint4* k4 = (const uint4*)krow;
    float d = 0.f;
#pragma unroll
    for (int i = 0; i < 8; i++) {
        uint4 kv = k4[i];
        d = fmaf(qf[8 * i + 0], bflo(kv.x), d);
        d = fmaf(qf[8 * i + 1], bfhi(kv.x), d);
        d = fmaf(qf[8 * i + 2], bflo(kv.y), d);
        d = fmaf(qf[8 * i + 3], bfhi(kv.y), d);
        d = fmaf(qf[8 * i + 4], bflo(kv.z), d);
        d = fmaf(qf[8 * i + 5], bfhi(kv.z), d);
        d = fmaf(qf[8 * i + 6], bflo(kv.w), d);
        d = fmaf(qf[8 * i + 7], bfhi(kv.w), d);
    }
    return d;
}

__global__ __launch_bounds__(64) void swa_kernel(
    const u16* __restrict__ qkv, const int* __restrict__ mask,
    u16* __restrict__ values)
{
    const int l = blockIdx.x * 64 + threadIdx.x;
    const int h = blockIdx.y;
    const int b = blockIdx.z;
    const size_t base_bl = (size_t)b * ATT_L;

    const u16* qrow = qkv + (base_bl + l) * ATT_C3 + h * 192;
    float qf[64];
    {
        const uint4* q4 = (const uint4*)qrow;
#pragma unroll
        for (int i = 0; i < 8; i++) {
            uint4 qv = q4[i];
            qf[8 * i + 0] = bflo(qv.x); qf[8 * i + 1] = bfhi(qv.x);
            qf[8 * i + 2] = bflo(qv.y); qf[8 * i + 3] = bfhi(qv.y);
            qf[8 * i + 4] = bflo(qv.z); qf[8 * i + 5] = bfhi(qv.z);
            qf[8 * i + 6] = bflo(qv.w); qf[8 * i + 7] = bfhi(qv.w);
        }
    }
    const int* mrow = mask + b * ATT_L;

    // pass 1: running max + denominator over all 65 window entries
    float m = -3.0e38f, den = 0.f;
#pragma unroll 1
    for (int p = 0; p < 65; p++) {
        int pos = l - 32 + p;
        float s = NEG_SCORE * 0.125f;
        if (pos >= 0 && pos < ATT_L && mrow[pos] != 0) {
            const u16* krow = qkv + (base_bl + pos) * ATT_C3 + h * 192 + 64;
            s = dot64(qf, krow) * 0.125f;
        }
        float mn = fmaxf(m, s);
        den = den * __expf(m - mn) + __expf(s - mn);
        m = mn;
    }

    float out[64];
#pragma unroll
    for (int i = 0; i < 64; i++) out[i] = 0.f;

    // pass 2: recompute scores, accumulate weighted V (invalid pos -> v==0)
#pragma unroll 1
    for (int p = 0; p < 65; p++) {
        int pos = l - 32 + p;
        if (pos < 0 || pos >= ATT_L) continue;
        float s = NEG_SCORE * 0.125f;
        if (mrow[pos] != 0) {
            const u16* krow = qkv + (base_bl + pos) * ATT_C3 + h * 192 + 64;
            s = dot64(qf, krow) * 0.125f;
        }
        float wgt = __expf(s - m);
        const uint4* v4 = (const uint4*)(qkv + (base_bl + pos) * ATT_C3 + h * 192 + 128);
#pragma unroll
        for (int i = 0; i < 8; i++) {
            uint4 vv = v4[i];
            out[8 * i + 0] = fmaf(wgt, bflo(vv.x), out[8 * i + 0]);
            out[8 * i + 1] = fmaf(wgt, bfhi(vv.x), out[8 * i + 1]);
            out[8 * i + 2] = fmaf(wgt, bflo(vv.y), out[8 * i + 2]);
            out[8 * i + 3] = fmaf(wgt, bfhi(vv.y), out[8 * i + 3]);
            out[8 * i + 4] = fmaf(wgt, bflo(vv.z), out[8 * i + 4]);
            out[8 * i + 5] = fmaf(wgt, bfhi(vv.z), out[8 * i + 5]);
            out[8 * i + 6] = fmaf(wgt, bflo(vv.w), out[8 * i + 6]);
            out[8 * i + 7] = fmaf(wgt, bfhi(vv.w), out[8 * i + 7]);
        }
    }

    float inv = 1.0f / den;
    u32* vout = (u32*)(values + (base_bl + l) * 1024 + h * 64);
#pragma unroll
    for (int i = 0; i < 32; i++) {
        u32 lo = f2bf(out[2 * i] * inv);
        u32 hi = f2bf(out[2 * i + 1] * inv);
        vout[i] = lo | (hi << 16);
    }
}

// =====================================================================
// B=2, L=2048, H=16, hd=64, E=1024, input_dim=1024, window=64 (W=65)
// inputs (fp32 per reference, mask int32):
//   x(4096x1024), padding_mask(2x2048 i32), W_qkv(3072x1024), b_qkv(3072),
//   W_o(1024x1024), b_o(1024).  out: fp32 4096x1024.
// ws layout (48 MB): qkv bf16 24MB | values bf16 8MB | xb 8MB | Wqkvb 6MB | Wob 2MB
// =====================================================================
extern "C" void kernel_launch(void* const* d_in, const int* in_sizes, int n_in,
                              void* d_out, int out_size, void* d_ws, size_t ws_size,
                              hipStream_t stream) {
    const float* x     = (const float*)d_in[0];
    const int*   pmask = (const int*)d_in[1];
    const float* Wqkv  = (const float*)d_in[2];
    const float* bqkv  = (const float*)d_in[3];
    const float* Wo    = (const float*)d_in[4];
    const float* bo    = (const float*)d_in[5];
    float* out = (float*)d_out;

    u16* qkv    = (u16*)d_ws;                          // 4096*3072
    u16* values = qkv    + (size_t)4096 * 3072;        // 4096*1024
    u16* xb     = values + (size_t)4096 * 1024;        // 4096*1024
    u16* Wqkvb  = xb     + (size_t)4096 * 1024;        // 3072*1024
    u16* Wob    = Wqkvb  + (size_t)3072 * 1024;        // 1024*1024

    // 0) convert fp32 inputs to bf16 (2% absmax threshold >> bf16 rounding)
    f32_to_bf16_kernel<<<4096 * 1024 / (256 * 8), 256, 0, stream>>>(x, xb);
    f32_to_bf16_kernel<<<3072 * 1024 / (256 * 8), 256, 0, stream>>>(Wqkv, Wqkvb);
    f32_to_bf16_kernel<<<1024 * 1024 / (256 * 8), 256, 0, stream>>>(Wo, Wob);

    // 1) qkv = x @ Wqkv^T + bqkv : M=4096 N=3072 K=1024 (bf16 out)
    gemm_bt_bias<true><<<dim3(3072 / 128, 4096 / 128), 256, 0, stream>>>(
        xb, Wqkvb, bqkv, qkv, 4096, 3072, 1024);

    // 2) sliding-window attention -> values (bf16)
    swa_kernel<<<dim3(2048 / 64, 16, 2), 64, 0, stream>>>(qkv, pmask, values);

    // 3) out = values @ Wo^T + bo : M=4096 N=1024 K=1024 (fp32 out)
    gemm_bt_bias<false><<<dim3(1024 / 128, 4096 / 128), 256, 0, stream>>>(
        values, Wob, bo, out, 4096, 1024, 1024);
}